// Round 17
// baseline (139.166 us; speedup 1.0000x reference)
//
#include <hip/hip_runtime.h>
#include <math.h>

// ============================================================================
// DIAGNOSTIC ROUND (R11/R14 protocol): kernel body is R16's mam_fused14,
// UNCHANGED (verified, absmax 0). kernel_launch fires it 5x back-to-back
// (idempotent). Purpose: single-launch dur_us cannot resolve a 15.4->11us
// kernel change under the +-9us harness offset; the marginal can:
//   kernel = (dur_us - 74.0) / 4     [R16 dur_1x = 74.0]
// Decides whether the instruction-granularity DS/VALU interleave reached the
// 7.7us DS-pipe floor (-> restore 1x, declare) or the serialization is
// architectural (-> restore 1x, declare plateau). Also lifts the kernel into
// the PMC top-5 for VALUBusy / bank-conflict / VGPR readout.
// ============================================================================

#define N_ 2048
#define K_ 512
#define J_ 256

typedef float f32x4 __attribute__((ext_vector_type(4)));
typedef float f32x2 __attribute__((ext_vector_type(2)));
typedef __attribute__((address_space(3))) float       lds_f;
typedef const __attribute__((address_space(1))) float glb_f;

#define MAX3(acc, a, b) asm("v_max3_f32 %0, %0, %1, %2" : "+v"(acc) : "v"(a), "v"(b))
#define MIN3(acc, a, b) asm("v_min3_f32 %0, %0, %1, %2" : "+v"(acc) : "v"(a), "v"(b))
#define SB() __builtin_amdgcn_sched_barrier(0)

__global__ __launch_bounds__(512, 2) void mam_fused14(
    const float* __restrict__ x, const float* __restrict__ w,
    const float* __restrict__ bias, float* __restrict__ out)
{
    __shared__ __align__(16) float sm[24576];   // 96 KB: x[2][64][128] | w[2][32][128]

    const int t    = threadIdx.x;
    const int lane = t & 63;
    const int kq   = __builtin_amdgcn_readfirstlane(t >> 6);   // wave 0..7

    // XCD-chunked bijective swizzle (256 = 8 * 32).
    const int wg0 = (int)blockIdx.x;
    const int wg  = (wg0 & 7) * 32 + (wg0 >> 3);
    const int bx  = wg & 7;             // j-block (32 cols)
    const int by  = wg >> 3;            // n-block (64 rows)
    const int n0  = by * 64;
    const int j0  = bx * 32;

    const int rn = lane >> 3;           // 0..7
    const int cj = lane & 7;            // 0..7

    float mx[8][4], mn[8][4];
#pragma unroll
    for (int i = 0; i < 8; ++i)
#pragma unroll
        for (int jj = 0; jj < 4; ++jj) {
            mx[i][jj] = -__builtin_inff();
            mn[i][jj] =  __builtin_inff();
        }

#define STAGE(buf, s)                                                          \
    {                                                                          \
        const int kb = (s) * 128;                                              \
        _Pragma("unroll")                                                      \
        for (int u = 0; u < 4; ++u) {   /* x: 32 loads, 4 per wave */          \
            const int li  = kq * 4 + u;                                        \
            const int row = 2 * li + (lane >> 5);                              \
            __builtin_amdgcn_global_load_lds(                                  \
                (glb_f*)(x + (size_t)(n0 + row) * K_ + kb                      \
                         + (((lane & 31) ^ (row & 7)) << 2)),                  \
                (lds_f*)(sm + (buf) * 8192 + li * 256), 16, 0, 0);             \
        }                                                                      \
        _Pragma("unroll")                                                      \
        for (int u = 0; u < 2; ++u) {   /* w: 16 loads, 2 per wave */          \
            const int wi  = kq * 2 + u;                                        \
            const int col = 2 * wi + (lane >> 5);                              \
            __builtin_amdgcn_global_load_lds(                                  \
                (glb_f*)(w + (size_t)(j0 + col) * K_ + kb                      \
                         + (((lane & 31) ^ (col & 7)) << 2)),                  \
                (lds_f*)(sm + 16384 + (buf) * 4096 + wi * 256), 16, 0, 0);     \
        }                                                                      \
    }

    f32x4 AX[8], AW[4], BX[8], BW[4];   // double-buffered read sets

#define PRO12(NX, NW, XA, WA)                                                  \
    asm volatile(                                                              \
        "ds_read_b128 %0, %12\n\t"                                             \
        "ds_read_b128 %1, %12 offset:4096\n\t"                                 \
        "ds_read_b128 %2, %12 offset:8192\n\t"                                 \
        "ds_read_b128 %3, %12 offset:12288\n\t"                                \
        "ds_read_b128 %4, %13\n\t"                                             \
        "ds_read_b128 %5, %13 offset:4096\n\t"                                 \
        "ds_read_b128 %6, %13 offset:8192\n\t"                                 \
        "ds_read_b128 %7, %13 offset:12288\n\t"                                \
        "ds_read_b128 %8, %13 offset:16384\n\t"                                \
        "ds_read_b128 %9, %13 offset:20480\n\t"                                \
        "ds_read_b128 %10, %13 offset:24576\n\t"                               \
        "ds_read_b128 %11, %13 offset:28672"                                   \
        : "=&v"(NW[0]), "=&v"(NW[1]), "=&v"(NW[2]), "=&v"(NW[3]),              \
          "=&v"(NX[0]), "=&v"(NX[1]), "=&v"(NX[2]), "=&v"(NX[3]),              \
          "=&v"(NX[4]), "=&v"(NX[5]), "=&v"(NX[6]), "=&v"(NX[7])               \
        : "v"(WA), "v"(XA));                                                   \
    SB();

#define READ2(D0, D1, BASE, I0, I1, NW)                                        \
    asm volatile("ds_read_b128 %0, %2 offset:" I0 "\n\t"                       \
                 "ds_read_b128 %1, %2 offset:" I1 "\n\t"                       \
                 "s_waitcnt lgkmcnt(" NW ")"                                   \
                 : "=&v"(D0), "=&v"(D1) : "v"(BASE));                          \
    SB();

#define READ1(D0, BASE, I0, NW)                                                \
    asm volatile("ds_read_b128 %0, %1 offset:" I0 "\n\t"                       \
                 "s_waitcnt lgkmcnt(" NW ")"                                   \
                 : "=&v"(D0) : "v"(BASE));                                     \
    SB();

#define WAITL(NW)                                                              \
    asm volatile("s_waitcnt lgkmcnt(" NW ")");                                 \
    SB();

#define COMPI(CX, CW, I)                                                       \
    {                                                                          \
        _Pragma("unroll")                                                      \
        for (int jj = 0; jj < 4; ++jj) {                                       \
            const f32x2 plo = CX[I].lo * CW[jj].lo;                            \
            const f32x2 phi = CX[I].hi * CW[jj].hi;                            \
            MAX3(mx[I][jj], plo.x, plo.y); MAX3(mx[I][jj], phi.x, phi.y);      \
            MIN3(mn[I][jj], plo.x, plo.y); MIN3(mn[I][jj], phi.x, phi.y);      \
        }                                                                      \
    }                                                                          \
    SB();

#define COMP_PAIR(CX, CW, NX, NW, XAN, WAN)                                    \
    READ2(NW[0], NW[1], WAN, "0", "4096", "9");      COMPI(CX, CW, 0)          \
    READ2(NW[2], NW[3], WAN, "8192", "12288", "10"); COMPI(CX, CW, 1)          \
    READ2(NX[0], NX[1], XAN, "0", "4096", "11");     COMPI(CX, CW, 2)          \
    READ2(NX[2], NX[3], XAN, "8192", "12288", "12"); COMPI(CX, CW, 3)          \
    READ1(NX[4], XAN, "16384", "12");                COMPI(CX, CW, 4)          \
    READ1(NX[5], XAN, "20480", "12");                COMPI(CX, CW, 5)          \
    READ1(NX[6], XAN, "24576", "12");                COMPI(CX, CW, 6)          \
    READ1(NX[7], XAN, "28672", "12");                COMPI(CX, CW, 7)

#define COMP_LAST(CX, CW)                                                      \
    WAITL("7") COMPI(CX, CW, 0)                                                \
    WAITL("6") COMPI(CX, CW, 1)                                                \
    WAITL("5") COMPI(CX, CW, 2)                                                \
    WAITL("4") COMPI(CX, CW, 3)                                                \
    WAITL("3") COMPI(CX, CW, 4)                                                \
    WAITL("2") COMPI(CX, CW, 5)                                                \
    WAITL("1") COMPI(CX, CW, 6)                                                \
    WAITL("0") COMPI(CX, CW, 7)

#define SLICE(buf)                                                             \
    {                                                                          \
        const unsigned xb0 = (buf) * 32768u + (unsigned)(rn * 512);            \
        const unsigned wb0 = 65536u + (buf) * 16384u + (unsigned)(cj * 512);   \
        const unsigned xa0 = xb0 + (unsigned)(((kq * 4 + 0) ^ rn) << 4);       \
        const unsigned wa0 = wb0 + (unsigned)(((kq * 4 + 0) ^ cj) << 4);       \
        const unsigned xa1 = xb0 + (unsigned)(((kq * 4 + 1) ^ rn) << 4);       \
        const unsigned wa1 = wb0 + (unsigned)(((kq * 4 + 1) ^ cj) << 4);       \
        const unsigned xa2 = xb0 + (unsigned)(((kq * 4 + 2) ^ rn) << 4);       \
        const unsigned wa2 = wb0 + (unsigned)(((kq * 4 + 2) ^ cj) << 4);       \
        const unsigned xa3 = xb0 + (unsigned)(((kq * 4 + 3) ^ rn) << 4);       \
        const unsigned wa3 = wb0 + (unsigned)(((kq * 4 + 3) ^ cj) << 4);       \
        PRO12(AX, AW, xa0, wa0);                                               \
        COMP_PAIR(AX, AW, BX, BW, xa1, wa1);                                   \
        COMP_PAIR(BX, BW, AX, AW, xa2, wa2);                                   \
        COMP_PAIR(AX, AW, BX, BW, xa3, wa3);                                   \
        COMP_LAST(BX, BW);                                                     \
    }

    STAGE(0, 0);
    __syncthreads();
    STAGE(1, 1);  SLICE(0);
    __syncthreads();
    STAGE(0, 2);  SLICE(1);
    __syncthreads();
    STAGE(1, 3);  SLICE(0);
    __syncthreads();
                  SLICE(1);
    __syncthreads();   // LDS about to be reused for the combine

#undef STAGE
#undef PRO12
#undef READ2
#undef READ1
#undef WAITL
#undef COMPI
#undef COMP_PAIR
#undef COMP_LAST
#undef SLICE

    // ---- Combine 8 k-chunks, two 16-col halves (cb[8][64][17] float2 = 68KB).
    float2* cb = (float2*)sm;
#pragma unroll
    for (int h = 0; h < 2; ++h) {
#pragma unroll
        for (int i = 0; i < 8; ++i)
#pragma unroll
            for (int jh = 0; jh < 2; ++jh) {
                const int jj = 2 * h + jh;
                float2 v; v.x = mx[i][jj]; v.y = mn[i][jj];
                cb[(kq * 64 + rn + 8 * i) * 17 + cj + 8 * jh] = v;
            }
        __syncthreads();
#pragma unroll
        for (int e = 0; e < 2; ++e) {
            const int o   = t + e * 512;       // 1024 outputs per half
            const int row = o >> 4;
            const int c16 = o & 15;
            float a = -__builtin_inff(), b = __builtin_inff();
#pragma unroll
            for (int c = 0; c < 8; ++c) {
                const float2 v = cb[(c * 64 + row) * 17 + c16];
                a = fmaxf(a, v.x);
                b = fminf(b, v.y);
            }
            const int j = j0 + 16 * h + c16;
            out[(size_t)(n0 + row) * J_ + j] = a + b + bias[j];
        }
        __syncthreads();
    }
}

extern "C" void kernel_launch(void* const* d_in, const int* in_sizes, int n_in,
                              void* d_out, int out_size, void* d_ws, size_t ws_size,
                              hipStream_t stream) {
    const float* x    = (const float*)d_in[0];
    const float* w    = (const float*)d_in[1];
    const float* bias = (const float*)d_in[2];
    float* out = (float*)d_out;

    dim3 grid(256);   // 32 n-blocks x 8 j-blocks, XCD-swizzled in-kernel
    // DIAGNOSTIC: 5 identical launches (idempotent). kernel = (dur - 74.0)/4.
    for (int r = 0; r < 5; ++r)
        mam_fused14<<<grid, 512, 0, stream>>>(x, w, bias, out);
}

// Round 18
// 72.005 us; speedup vs baseline: 1.9327x; 1.9327x over previous
//
#include <hip/hip_runtime.h>
#include <math.h>

// ============================================================================
// FINAL KERNEL (restored R10 mam_fused11 — session-best: kernel 15.2us
// offset-free [R11 5x-marginal], dur_1x 71.5us, absmax 0).
// Session ledger (offset-free marginals): compiler-sched 15.3 / this 15.2 /
// 2blk+pk_mul 15.4 / addr-rotation 15.5 / fine-interleave 16.3 — all equal
// the serialized pipe sum (DS 18.4Kcyc + VALU 16.4Kcyc + ~2.8us fixed).
// DS-issue/VALU overlap is not achievable by software schedule on this
// workload; fatter tiles are VGPR-barred. This is the structural plateau.
// ============================================================================

#define N_ 2048
#define K_ 512
#define J_ 256

typedef float f32x4 __attribute__((ext_vector_type(4)));
typedef __attribute__((address_space(3))) float       lds_f;
typedef const __attribute__((address_space(1))) float glb_f;

#define MAX3(acc, a, b) asm("v_max3_f32 %0, %0, %1, %2" : "+v"(acc) : "v"(a), "v"(b))
#define MIN3(acc, a, b) asm("v_min3_f32 %0, %0, %1, %2" : "+v"(acc) : "v"(a), "v"(b))

__global__ __launch_bounds__(512, 2) void mam_fused11(
    const float* __restrict__ x, const float* __restrict__ w,
    const float* __restrict__ bias, float* __restrict__ out)
{
    __shared__ __align__(16) float sm[24576];   // 96 KB: x[2][64][128] | w[2][32][128]

    const int t    = threadIdx.x;
    const int lane = t & 63;
    const int kq   = __builtin_amdgcn_readfirstlane(t >> 6);   // wave 0..7

    const int wg0 = (int)blockIdx.x;
    const int wg  = (wg0 & 7) * 32 + (wg0 >> 3);
    const int bx  = wg & 7;             // j-block (32 cols)
    const int by  = wg >> 3;            // n-block (64 rows)
    const int n0  = by * 64;
    const int j0  = bx * 32;

    const int rn = lane >> 3;           // 0..7
    const int cj = lane & 7;            // 0..7

    float mx[8][4], mn[8][4];
#pragma unroll
    for (int i = 0; i < 8; ++i)
#pragma unroll
        for (int jj = 0; jj < 4; ++jj) {
            mx[i][jj] = -__builtin_inff();
            mn[i][jj] =  __builtin_inff();
        }

#define STAGE(buf, s)                                                          \
    {                                                                          \
        const int kb = (s) * 128;                                              \
        _Pragma("unroll")                                                      \
        for (int u = 0; u < 4; ++u) {   /* x: 32 loads, 4 per wave */          \
            const int li  = kq * 4 + u;                                        \
            const int row = 2 * li + (lane >> 5);                              \
            __builtin_amdgcn_global_load_lds(                                  \
                (glb_f*)(x + (size_t)(n0 + row) * K_ + kb                      \
                         + (((lane & 31) ^ (row & 7)) << 2)),                  \
                (lds_f*)(sm + (buf) * 8192 + li * 256), 16, 0, 0);             \
        }                                                                      \
        _Pragma("unroll")                                                      \
        for (int u = 0; u < 2; ++u) {   /* w: 16 loads, 2 per wave */          \
            const int wi  = kq * 2 + u;                                        \
            const int col = 2 * wi + (lane >> 5);                              \
            __builtin_amdgcn_global_load_lds(                                  \
                (glb_f*)(w + (size_t)(j0 + col) * K_ + kb                      \
                         + (((lane & 31) ^ (col & 7)) << 2)),                  \
                (lds_f*)(sm + 16384 + (buf) * 4096 + wi * 256), 16, 0, 0);     \
        }                                                                      \
    }

    f32x4 AXv[8], AWv[4], BXv[8], BWv[4];   // double-buffered read sets

#define READQ(Xv, Wv, xa, wa, WCNT)                                            \
    asm volatile(                                                              \
        "ds_read_b128 %0, %12\n\t"                                             \
        "ds_read_b128 %1, %12 offset:4096\n\t"                                 \
        "ds_read_b128 %2, %12 offset:8192\n\t"                                 \
        "ds_read_b128 %3, %12 offset:12288\n\t"                                \
        "ds_read_b128 %4, %12 offset:16384\n\t"                                \
        "ds_read_b128 %5, %12 offset:20480\n\t"                                \
        "ds_read_b128 %6, %12 offset:24576\n\t"                                \
        "ds_read_b128 %7, %12 offset:28672\n\t"                                \
        "ds_read_b128 %8, %13\n\t"                                             \
        "ds_read_b128 %9, %13 offset:4096\n\t"                                 \
        "ds_read_b128 %10, %13 offset:8192\n\t"                                \
        "ds_read_b128 %11, %13 offset:12288\n\t"                               \
        WCNT                                                                   \
        : "=&v"(Xv[0]), "=&v"(Xv[1]), "=&v"(Xv[2]), "=&v"(Xv[3]),              \
          "=&v"(Xv[4]), "=&v"(Xv[5]), "=&v"(Xv[6]), "=&v"(Xv[7]),              \
          "=&v"(Wv[0]), "=&v"(Wv[1]), "=&v"(Wv[2]), "=&v"(Wv[3])               \
        : "v"(xa), "v"(wa));                                                   \
    __builtin_amdgcn_sched_barrier(0);

#define COMPQ(Xv, Wv)                                                          \
    _Pragma("unroll")                                                          \
    for (int i = 0; i < 8; ++i)                                                \
        _Pragma("unroll")                                                      \
        for (int jj = 0; jj < 4; ++jj) {                                       \
            const f32x4 a = Xv[i], b = Wv[jj];                                 \
            const float p0 = a.x * b.x, p1 = a.y * b.y;                        \
            const float p2 = a.z * b.z, p3 = a.w * b.w;                        \
            MAX3(mx[i][jj], p0, p1); MAX3(mx[i][jj], p2, p3);                  \
            MIN3(mn[i][jj], p0, p1); MIN3(mn[i][jj], p2, p3);                  \
        }

#define COMP(buf)                                                              \
    {                                                                          \
        const unsigned xb0 = (buf) * 32768u + (unsigned)(rn * 512);            \
        const unsigned wb0 = 65536u + (buf) * 16384u + (unsigned)(cj * 512);   \
        const unsigned xa0 = xb0 + (unsigned)((((kq * 4 + 0) ^ rn)) << 4);     \
        const unsigned wa0 = wb0 + (unsigned)((((kq * 4 + 0) ^ cj)) << 4);     \
        const unsigned xa1 = xb0 + (unsigned)((((kq * 4 + 1) ^ rn)) << 4);     \
        const unsigned wa1 = wb0 + (unsigned)((((kq * 4 + 1) ^ cj)) << 4);     \
        const unsigned xa2 = xb0 + (unsigned)((((kq * 4 + 2) ^ rn)) << 4);     \
        const unsigned wa2 = wb0 + (unsigned)((((kq * 4 + 2) ^ cj)) << 4);     \
        const unsigned xa3 = xb0 + (unsigned)((((kq * 4 + 3) ^ rn)) << 4);     \
        const unsigned wa3 = wb0 + (unsigned)((((kq * 4 + 3) ^ cj)) << 4);     \
        READQ(AXv, AWv, xa0, wa0, "");                                         \
        READQ(BXv, BWv, xa1, wa1, "s_waitcnt lgkmcnt(12)\n\t");                \
        COMPQ(AXv, AWv);                                                       \
        READQ(AXv, AWv, xa2, wa2, "s_waitcnt lgkmcnt(12)\n\t");                \
        COMPQ(BXv, BWv);                                                       \
        READQ(BXv, BWv, xa3, wa3, "s_waitcnt lgkmcnt(12)\n\t");                \
        COMPQ(AXv, AWv);                                                       \
        asm volatile("s_waitcnt lgkmcnt(0)");                                  \
        __builtin_amdgcn_sched_barrier(0);                                     \
        COMPQ(BXv, BWv);                                                       \
    }

    STAGE(0, 0);
    __syncthreads();
    STAGE(1, 1);  COMP(0);
    __syncthreads();
    STAGE(0, 2);  COMP(1);
    __syncthreads();
    STAGE(1, 3);  COMP(0);
    __syncthreads();
                  COMP(1);
    __syncthreads();   // LDS about to be reused for the combine

#undef STAGE
#undef READQ
#undef COMPQ
#undef COMP

    // ---- Combine 8 k-chunks, two 16-col halves (cb[8][64][17] float2 = 68KB).
    float2* cb = (float2*)sm;
#pragma unroll
    for (int h = 0; h < 2; ++h) {
#pragma unroll
        for (int i = 0; i < 8; ++i)
#pragma unroll
            for (int jh = 0; jh < 2; ++jh) {
                const int jj = 2 * h + jh;
                float2 v; v.x = mx[i][jj]; v.y = mn[i][jj];
                cb[(kq * 64 + rn + 8 * i) * 17 + cj + 8 * jh] = v;
            }
        __syncthreads();
#pragma unroll
        for (int e = 0; e < 2; ++e) {
            const int o   = t + e * 512;       // 1024 outputs per half
            const int row = o >> 4;
            const int c16 = o & 15;
            float a = -__builtin_inff(), b = __builtin_inff();
#pragma unroll
            for (int c = 0; c < 8; ++c) {
                const float2 v = cb[(c * 64 + row) * 17 + c16];
                a = fmaxf(a, v.x);
                b = fminf(b, v.y);
            }
            const int j = j0 + 16 * h + c16;
            out[(size_t)(n0 + row) * J_ + j] = a + b + bias[j];
        }
        __syncthreads();
    }
}

extern "C" void kernel_launch(void* const* d_in, const int* in_sizes, int n_in,
                              void* d_out, int out_size, void* d_ws, size_t ws_size,
                              hipStream_t stream) {
    const float* x    = (const float*)d_in[0];
    const float* w    = (const float*)d_in[1];
    const float* bias = (const float*)d_in[2];
    float* out = (float*)d_out;

    dim3 grid(256);   // 32 n-blocks x 8 j-blocks, XCD-swizzled in-kernel
    mam_fused11<<<grid, 512, 0, stream>>>(x, w, bias, out);
}